// Round 16
// baseline (247.616 us; speedup 1.0000x reference)
//
#include <hip/hip_runtime.h>
#include <hip/hip_bf16.h>
#include <stdint.h>
#include <math.h>

// PANConcDQL round 16 -- math identical to r15 (passed, absmax 0.0).
// Changes: (1) memset+scatter+extract fused into r16_build (LDS bitsets,
// direct CSR-plane writes, no spill); (2) poolgat: wave-shfl stat reductions,
// GAT staging padded to 448 -> fixed 7-iter unconditional-load inner loop;
// (3) head: shfl reductions. 4 dispatches total.
#define BB   16
#define NPn  512
#define LLp  20
#define NAa  50
#define KKk  410
#define NNt  (BB * NPn)   // 8192
#define EEe  (6 * NNt)    // 49152
#define NFf  13
#define KPAD 416
#define KP2  448          // padded staging width (7*64)
#define EPSf 1e-5f
#define QCLMP 1e6f
#define MAXD 28
#define PADR 512

__device__ __forceinline__ float r16_sane(float v) {
    if (!(v == v)) return 0.0f;
    return fminf(fmaxf(v, -1e15f), 1e15f);
}

// ---------------------------------------------------------------------------
// K1: per-graph LDS bitset build (fwd + trs) -> CSR planes. 16 x 512.
__global__ __launch_bounds__(512) void r16_build(
    const int* __restrict__ ei,
    unsigned short* __restrict__ csrF, unsigned short* __restrict__ csrT)
{
    __shared__ uint32_t fw[NPn * 16];     // 32 KB
    __shared__ uint32_t tr[NPn * 16];     // 32 KB
    const int b = blockIdx.x, t = threadIdx.x;
#pragma unroll
    for (int w = 0; w < 16; ++w) { fw[t * 16 + w] = 0u; tr[t * 16 + w] = 0u; }
    __syncthreads();
    for (int e = t; e < EEe; e += 512) {
        const int src = ei[e], dst = ei[EEe + e];
        if ((dst >> 9) == b)
            atomicOr(&fw[(dst & 511) * 16 + ((src & 511) >> 5)], 1u << (src & 31));
        if ((src >> 9) == b)
            atomicOr(&tr[(src & 511) * 16 + ((dst & 511) >> 5)], 1u << (dst & 31));
    }
    __syncthreads();
    const int node = b * 512 + t;
    {
        int cnt = 0;
        for (int w = 0; w < 16; ++w) {
            uint32_t bits = fw[t * 16 + w];
            while (bits) {
                const int u = (w << 5) + __ffs(bits) - 1;
                bits &= bits - 1;
                if (cnt < MAXD) csrF[(size_t)cnt * 8192 + node] = (unsigned short)u;
                ++cnt;
            }
        }
        for (int j = cnt; j < MAXD; ++j) csrF[(size_t)j * 8192 + node] = PADR;
    }
    {
        int cnt = 0;
        for (int w = 0; w < 16; ++w) {
            uint32_t bits = tr[t * 16 + w];
            while (bits) {
                const int u = (w << 5) + __ffs(bits) - 1;
                bits &= bits - 1;
                if (cnt < MAXD) csrT[(size_t)cnt * 8192 + node] = (unsigned short)u;
                ++cnt;
            }
        }
        for (int j = cnt; j < MAXD; ++j) csrT[(size_t)j * 8192 + node] = PADR;
    }
}

// ---------------------------------------------------------------------------
// K2: mid, grid (16,20) x 512 (verbatim r15_mid -- no spill, compile-time idx).
__global__ __launch_bounds__(512) void r16_mid(
    const float* __restrict__ x,
    const unsigned short* __restrict__ csrF,
    const unsigned short* __restrict__ csrT,
    const float* __restrict__ panw,
    const float* __restrict__ l1w, const float* __restrict__ l1b,
    float* __restrict__ h_raw, float* __restrict__ colsum,
    uint32_t* __restrict__ Rb)
{
    __shared__ __align__(16) uint32_t sbuf[1047];
    float* pa  = (float*)sbuf;             // 513
    float* pb  = (float*)(sbuf + 513);     // 513
    float* wsh = (float*)(sbuf + 1026);    // 21
    const int b = blockIdx.x, y = blockIdx.y, t = threadIdx.x;
    const int node = b * 512 + t;

    if (y < 4) {
        const int c = y;
        int iF[MAXD];
#pragma unroll
        for (int j = 0; j < MAXD; ++j) iF[j] = (int)csrF[(size_t)j * 8192 + node];
        if (t < 21) wsh[t] = panw[t];

        pa[t] = 1.0f;
        if (t == 0) { pa[512] = 0.0f; pb[512] = 0.0f; }
        __syncthreads();
        float dacc = wsh[0];
        {
            float* rp = pa; float* rn = pb;
            for (int i = 1; i <= LLp; ++i) {
                float tv[MAXD];
#pragma unroll
                for (int j = 0; j < MAXD; ++j) tv[j] = rp[iF[j]];
                float s = 0.0f;
#pragma unroll
                for (int j = 0; j < MAXD; ++j) s += tv[j];
                rn[t] = s;
                dacc += wsh[i] * s;
                __syncthreads();
                float* tp = rp; rp = rn; rn = tp;
            }
        }
        const float d0 = (dacc > 0.0f) ? 1.0f / sqrtf(dacc) : 0.0f;

        int idx[MAXD];
        if (c == 3) {
#pragma unroll
            for (int j = 0; j < MAXD; ++j) idx[j] = (int)csrT[(size_t)j * 8192 + node];
        } else {
#pragma unroll
            for (int j = 0; j < MAXD; ++j) idx[j] = iF[j];
        }
        float seed;
        if (c < 3) {
            float xw = 0.0f;
            const float* xr = x + (size_t)node * NFf;
            for (int f = 0; f < NFf; ++f) xw += xr[f] * l1w[f * 3 + c];
            seed = d0 * xw;
        } else {
            seed = d0;
        }
        pa[t] = seed;
        if (t == 0) { pa[512] = 0.0f; pb[512] = 0.0f; }
        __syncthreads();
        float acc = wsh[0] * seed;
        {
            float* rp = pa; float* rn = pb;
            for (int i = 1; i <= LLp; ++i) {
                float tv[MAXD];
#pragma unroll
                for (int j = 0; j < MAXD; ++j) tv[j] = rp[idx[j]];
                float s = 0.0f;
#pragma unroll
                for (int j = 0; j < MAXD; ++j) s += tv[j];
                rn[t] = s;
                acc += wsh[i] * s;
                __syncthreads();
                float* tp = rp; rp = rn; rn = tp;
            }
        }
        if (c < 3) h_raw[(size_t)node * 3 + c] = r16_sane(d0 * acc + l1b[c]);
        else       colsum[node] = r16_sane(d0 * acc);
    } else {
        const int q = y - 4;
        int iF[MAXD];
#pragma unroll
        for (int j = 0; j < MAXD; ++j) iF[j] = (int)csrF[(size_t)j * 8192 + node];
        uint32_t* R1 = sbuf;
        uint32_t* R2 = sbuf + 513;
        R1[t] = ((t >> 5) == q) ? (1u << (t & 31)) : 0u;
        if (t == 0) { R1[512] = 0u; R2[512] = 0u; }
        __syncthreads();
        uint32_t* Rp = R1; uint32_t* Rn = R2;
        for (int i = 0; i < LLp; ++i) {
            uint32_t tv[MAXD];
#pragma unroll
            for (int j = 0; j < MAXD; ++j) tv[j] = Rp[iF[j]];
            uint32_t r = Rp[t];
#pragma unroll
            for (int j = 0; j < MAXD; ++j) r |= tv[j];
            Rn[t] = r;
            __syncthreads();
            uint32_t* tp = Rp; Rp = Rn; Rn = tp;
        }
        Rb[(size_t)node * 16 + q] = Rp[t];
    }
}

// ---------------------------------------------------------------------------
// K3: poolgat, grid (16,8) x 512. Shfl-based stats; padded GAT staging (448)
// with fixed 7-iteration unconditional-load inner loop.
__global__ __launch_bounds__(512) void r16_poolgat(
    const float* __restrict__ h_raw,
    const float* __restrict__ colsum,
    const uint32_t* __restrict__ Rb,
    const float* n1w, const float* n1b, const float* n1ms,
    const float* poolp, const float* poolb,
    const float* gwl, const float* gbl,
    const float* gwr, const float* gbr,
    const float* gatt, const float* gbias,
    float* __restrict__ x1,
    float* __restrict__ g_raw)
{
    __shared__ __align__(16) uint32_t pg[10744];
    float* sc   = (float*)pg;                  // 512
    float* mv   = (float*)(pg + 512);          // 8
    float* wred = (float*)(pg + 520);          // 48
    float* xpS  = (float*)(pg + 568);          // 1248 (416*3)
    int*   kidx = (int*)(pg + 1816);           // 416
    float* xlS  = (float*)(pg + 2232);         // 1344 (448*3)
    uint32_t* RT = pg + 3576;                  // 16*448 = 7168
    const int b = blockIdx.x, y = blockIdx.y, t = threadIdx.x;
    const int lane = t & 63, wv = t >> 6;
    const float inv_n = 1.0f / (float)NNt;

    // ---- norm1 stats: means via wave shfl + cross-wave combine ----
    float hv0[16], hv1[16], hv2[16];
    float p0 = 0.0f, p1 = 0.0f, p2 = 0.0f;
#pragma unroll
    for (int k = 0; k < 16; ++k) {
        const float* hr = h_raw + (size_t)(k * 512 + t) * 3;
        hv0[k] = hr[0]; hv1[k] = hr[1]; hv2[k] = hr[2];
        p0 += hv0[k]; p1 += hv1[k]; p2 += hv2[k];
    }
#pragma unroll
    for (int off = 32; off; off >>= 1) {
        p0 += __shfl_xor(p0, off); p1 += __shfl_xor(p1, off); p2 += __shfl_xor(p2, off);
    }
    if (lane == 0) { wred[wv * 3 + 0] = p0; wred[wv * 3 + 1] = p1; wred[wv * 3 + 2] = p2; }
    __syncthreads();
    if (t < 3) {
        float s = 0.0f;
        for (int w = 0; w < 8; ++w) s += wred[w * 3 + t];
        mv[t] = s * inv_n;
    }
    __syncthreads();
    const float mm0 = n1ms[0] * mv[0], mm1 = n1ms[1] * mv[1], mm2 = n1ms[2] * mv[2];
    float q0 = 0.0f, q1 = 0.0f, q2 = 0.0f;
#pragma unroll
    for (int k = 0; k < 16; ++k) {
        const float d0 = hv0[k] - mm0, d1 = hv1[k] - mm1, d2 = hv2[k] - mm2;
        q0 += d0 * d0; q1 += d1 * d1; q2 += d2 * d2;
    }
#pragma unroll
    for (int off = 32; off; off >>= 1) {
        q0 += __shfl_xor(q0, off); q1 += __shfl_xor(q1, off); q2 += __shfl_xor(q2, off);
    }
    if (lane == 0) { wred[wv * 3 + 0] = q0; wred[wv * 3 + 1] = q1; wred[wv * 3 + 2] = q2; }
    __syncthreads();
    if (t < 3) {
        float s = 0.0f;
        for (int w = 0; w < 8; ++w) s += wred[w * 3 + t];
        mv[3 + t] = s * inv_n;
    }
    __syncthreads();

    const float mmv[3] = { mm0, mm1, mm2 };
    float xv[3];
#pragma unroll
    for (int c = 0; c < 3; ++c) {
        const float iv = 1.0f / sqrtf(fmaxf(mv[3 + c], 0.0f) + EPSf);
        const float o  = h_raw[(size_t)(b * NPn + t) * 3 + c] - mmv[c];
        const float tt = n1w[c] * o * iv + n1b[c];
        xv[c] = fmaxf(tt, 0.0f);
        if (y == 0) x1[(size_t)(b * NPn + t) * 3 + c] = xv[c];
    }
    float s = poolb[0] * (xv[0] * poolp[0] + xv[1] * poolp[1] + xv[2] * poolp[2])
            + poolb[1] * colsum[b * NPn + t];
    s = tanhf(s);
    if (!(s == s)) s = 0.0f;
    sc[t] = s;
    __syncthreads();
    int cnt = 0;
    for (int u = 0; u < NPn; ++u) {
        const float su = sc[u];
        cnt += ((su > s) || (su == s && u < t)) ? 1 : 0;   // lax.top_k tie-break
    }
    if (cnt < KKk) {                       // rank-count bijection
        kidx[cnt] = t;
        xpS[cnt * 3 + 0] = xv[0] * s;
        xpS[cnt * 3 + 1] = xv[1] * s;
        xpS[cnt * 3 + 2] = xv[2] * s;
    }
    __syncthreads();

    // ---- GAT staging (padded to 448: pad xl = 0, mask words = 0) ----
    float Wl[9], Wr[9];
#pragma unroll
    for (int i2 = 0; i2 < 9; ++i2) { Wl[i2] = gwl[i2]; Wr[i2] = gwr[i2]; }
    const float Bl0 = gbl[0], Bl1 = gbl[1], Bl2 = gbl[2];
    const float Br0 = gbr[0], Br1 = gbr[1], Br2 = gbr[2];
    const float At0 = gatt[0], At1 = gatt[1], At2 = gatt[2];
    const float Gb0 = gbias[0], Gb1 = gbias[1], Gb2 = gbias[2];
    if (t < KP2) {
        const int j = t;
        if (j < KKk) {
            const float c0 = xpS[j * 3 + 0];
            const float c1 = xpS[j * 3 + 1];
            const float c2 = xpS[j * 3 + 2];
            xlS[j * 3 + 0] = c0 * Wl[0] + c1 * Wl[3] + c2 * Wl[6] + Bl0;
            xlS[j * 3 + 1] = c0 * Wl[1] + c1 * Wl[4] + c2 * Wl[7] + Bl1;
            xlS[j * 3 + 2] = c0 * Wl[2] + c1 * Wl[5] + c2 * Wl[8] + Bl2;
            const uint32_t* rr = Rb + (size_t)(b * NPn + kidx[j]) * 16;
#pragma unroll
            for (int w = 0; w < 16; ++w) RT[w * KP2 + j] = rr[w];
        } else {
            xlS[j * 3 + 0] = 0.0f; xlS[j * 3 + 1] = 0.0f; xlS[j * 3 + 2] = 0.0f;
#pragma unroll
            for (int w = 0; w < 16; ++w) RT[w * KP2 + j] = 0u;
        }
    }
    __syncthreads();

    // ---- GAT rows: 64 waves/graph; fixed 7-iter unconditional-load loop ----
    const int wid = y * 8 + wv;                    // 0..63
    for (int i = wid; i < KKk; i += 64) {
        const float c0 = xpS[i * 3 + 0];
        const float c1 = xpS[i * 3 + 1];
        const float c2 = xpS[i * 3 + 2];
        const float xr0 = c0 * Wr[0] + c1 * Wr[3] + c2 * Wr[6] + Br0;
        const float xr1 = c0 * Wr[1] + c1 * Wr[4] + c2 * Wr[7] + Br1;
        const float xr2 = c0 * Wr[2] + c1 * Wr[5] + c2 * Wr[8] + Br2;
        const int bi = kidx[i];
        const uint32_t mbit = 1u << (bi & 31);
        const uint32_t* Rw = &RT[(bi >> 5) * KP2];
        float mx = -3e38f, lsum = 0.0f, b0 = 0.0f, b1 = 0.0f, b2 = 0.0f;
#pragma unroll
        for (int it = 0; it < 7; ++it) {
            const int j = lane + it * 64;          // < 448
            const uint32_t rw = Rw[j];             // unconditional batched loads
            const float xl0 = xlS[j * 3 + 0];
            const float xl1 = xlS[j * 3 + 1];
            const float xl2 = xlS[j * 3 + 2];
            const bool valid = (rw & mbit) || (j == i);   // pads auto-invalid
            float e0 = xr0 + xl0; e0 = e0 > 0.0f ? e0 : 0.2f * e0;
            float e1 = xr1 + xl1; e1 = e1 > 0.0f ? e1 : 0.2f * e1;
            float e2 = xr2 + xl2; e2 = e2 > 0.0f ? e2 : 0.2f * e2;
            const float sv = At0 * e0 + At1 * e1 + At2 * e2;
            if (valid) {
                if (sv > mx) {
                    const float r = __expf(mx - sv);
                    lsum *= r; b0 *= r; b1 *= r; b2 *= r;
                    mx = sv;
                }
                const float pj = __expf(sv - mx);
                lsum += pj;
                b0 += pj * xl0; b1 += pj * xl1; b2 += pj * xl2;
            }
        }
#pragma unroll
        for (int off = 32; off; off >>= 1) {       // butterfly LSE merge
            const float mo = __shfl_xor(mx, off);
            const float lo = __shfl_xor(lsum, off);
            const float d0 = __shfl_xor(b0, off);
            const float d1 = __shfl_xor(b1, off);
            const float d2 = __shfl_xor(b2, off);
            const float M  = fmaxf(mx, mo);
            const float ea = __expf(mx - M), eb = __expf(mo - M);
            lsum = lsum * ea + lo * eb;
            b0 = b0 * ea + d0 * eb;
            b1 = b1 * ea + d1 * eb;
            b2 = b2 * ea + d2 * eb;
            mx = M;
        }
        if (lane == 0) {
            const float rl = 1.0f / fmaxf(lsum, 1e-30f);
            g_raw[(size_t)(b * KPAD + i) * 3 + 0] = r16_sane(b0 * rl + Gb0);
            g_raw[(size_t)(b * KPAD + i) * 3 + 1] = r16_sane(b1 * rl + Gb1);
            g_raw[(size_t)(b * KPAD + i) * 3 + 2] = r16_sane(b2 * rl + Gb2);
        }
    }
}

// ---------------------------------------------------------------------------
// K4: GraphNorm2 + relu, add-pool, feat gather, dueling head (shfl stats).
__global__ __launch_bounds__(512) void r16_head(
    const float* __restrict__ g_raw,
    const float* __restrict__ x1,
    const float* __restrict__ x,
    const int* __restrict__ cnid,
    const int* __restrict__ amask,
    const float* n2w, const float* n2b, const float* n2ms,
    const float* v1w, const float* v1b,
    const float* v2w, const float* v2b,
    const float* v3w, const float* v3b,
    const float* a1w, const float* a1b,
    const float* a2w, const float* a2b,
    const float* a3w, const float* a3b,
    float* __restrict__ out)
{
    __shared__ float wred[24];
    __shared__ float mv[6];
    __shared__ float gp[3];
    __shared__ float feat[19];
    __shared__ float h1a[10], h1v[10], h2a[5], h2v[5];
    __shared__ float a3[50];
    __shared__ float vout_s, amean_s;
    const int b = blockIdx.x, t = threadIdx.x;
    const int lane = t & 63, wv = t >> 6;
    const float denom = 1.0f / (float)(BB * KKk);

    float gv0[13], gv1[13], gv2[13];
    float p0 = 0.0f, p1 = 0.0f, p2 = 0.0f;
#pragma unroll
    for (int k = 0; k < 13; ++k) {
        const int r = k * 512 + t;
        float q0 = 0.0f, q1 = 0.0f, q2 = 0.0f;
        if (r < BB * KKk) {
            const int bq = r / KKk, iq = r - bq * KKk;
            const float* gr = g_raw + (size_t)(bq * KPAD + iq) * 3;
            q0 = gr[0]; q1 = gr[1]; q2 = gr[2];
        }
        gv0[k] = q0; gv1[k] = q1; gv2[k] = q2;
        p0 += q0; p1 += q1; p2 += q2;
    }
#pragma unroll
    for (int off = 32; off; off >>= 1) {
        p0 += __shfl_xor(p0, off); p1 += __shfl_xor(p1, off); p2 += __shfl_xor(p2, off);
    }
    if (lane == 0) { wred[wv * 3 + 0] = p0; wred[wv * 3 + 1] = p1; wred[wv * 3 + 2] = p2; }
    __syncthreads();
    if (t < 3) {
        float s = 0.0f;
        for (int w = 0; w < 8; ++w) s += wred[w * 3 + t];
        mv[t] = s * denom;
    }
    __syncthreads();
    const float mm0 = n2ms[0] * mv[0], mm1 = n2ms[1] * mv[1], mm2 = n2ms[2] * mv[2];
    float q0a = 0.0f, q1a = 0.0f, q2a = 0.0f;
#pragma unroll
    for (int k = 0; k < 13; ++k) {
        const int r = k * 512 + t;
        if (r < BB * KKk) {
            const float d0 = gv0[k] - mm0, d1 = gv1[k] - mm1, d2 = gv2[k] - mm2;
            q0a += d0 * d0; q1a += d1 * d1; q2a += d2 * d2;
        }
    }
#pragma unroll
    for (int off = 32; off; off >>= 1) {
        q0a += __shfl_xor(q0a, off); q1a += __shfl_xor(q1a, off); q2a += __shfl_xor(q2a, off);
    }
    if (lane == 0) { wred[wv * 3 + 0] = q0a; wred[wv * 3 + 1] = q1a; wred[wv * 3 + 2] = q2a; }
    __syncthreads();
    if (t < 3) {
        float s = 0.0f;
        for (int w = 0; w < 8; ++w) s += wred[w * 3 + t];
        mv[3 + t] = s * denom;
    }
    __syncthreads();

    const float mmv[3] = { mm0, mm1, mm2 };
    float s3[3] = { 0.0f, 0.0f, 0.0f };
    if (t < KKk) {
        const size_t r = (size_t)(b * KPAD + t) * 3;
#pragma unroll
        for (int c = 0; c < 3; ++c) {
            const float iv = 1.0f / sqrtf(fmaxf(mv[3 + c], 0.0f) + EPSf);
            s3[c] = fmaxf((g_raw[r + c] - mmv[c]) * iv * n2w[c] + n2b[c], 0.0f);
        }
    }
    // gp via shfl reduction
    float g0 = s3[0], g1 = s3[1], g2 = s3[2];
#pragma unroll
    for (int off = 32; off; off >>= 1) {
        g0 += __shfl_xor(g0, off); g1 += __shfl_xor(g1, off); g2 += __shfl_xor(g2, off);
    }
    if (lane == 0) { wred[wv * 3 + 0] = g0; wred[wv * 3 + 1] = g1; wred[wv * 3 + 2] = g2; }
    __syncthreads();
    if (t < 3) {
        float s = 0.0f;
        for (int w = 0; w < 8; ++w) s += wred[w * 3 + t];
        gp[t] = s;
    }
    __syncthreads();

    if (t < 19) {
        const int gidx = cnid[b] + b * KKk;        // faithful: pooled-K offsets
        float fv;
        if (t < 13)      fv = x[(size_t)gidx * NFf + t];
        else if (t < 16) fv = x1[(size_t)gidx * 3 + (t - 13)];
        else             fv = gp[t - 16];
        feat[t] = fv;
    }
    __syncthreads();

    if (t < 10) {
        float s = a1b[t];
        for (int f = 0; f < 19; ++f) s += feat[f] * a1w[f * 10 + t];
        h1a[t] = fmaxf(s, 0.0f);
    } else if (t >= 64 && t < 74) {
        const int j = t - 64;
        float s = v1b[j];
        for (int f = 0; f < 19; ++f) s += feat[f] * v1w[f * 10 + j];
        h1v[j] = fmaxf(s, 0.0f);
    }
    __syncthreads();
    if (t < 5) {
        float s = a2b[t];
        for (int k = 0; k < 10; ++k) s += h1a[k] * a2w[k * 5 + t];
        h2a[t] = fmaxf(s, 0.0f);
    } else if (t >= 64 && t < 69) {
        const int j = t - 64;
        float s = v2b[j];
        for (int k = 0; k < 10; ++k) s += h1v[k] * v2w[k * 5 + j];
        h2v[j] = fmaxf(s, 0.0f);
    }
    __syncthreads();
    if (t < 50) {
        float s = a3b[t];
        for (int k = 0; k < 5; ++k) s += h2a[k] * a3w[k * 50 + t];
        a3[t] = s;
    } else if (t == 64) {
        float s = v3b[0];
        for (int k = 0; k < 5; ++k) s += h2v[k] * v3w[k];
        vout_s = s;
    }
    __syncthreads();
    if (t == 0) {
        float s = 0.0f;
        for (int k = 0; k < 50; ++k) s += a3[k];
        amean_s = s * (1.0f / 50.0f);
    }
    __syncthreads();
    if (t < 50) {
        float q = vout_s + a3[t] - amean_s;
        if (!(q == q)) q = 0.0f;
        q = fminf(fmaxf(q, -QCLMP), QCLMP);
        out[b * NAa + t] = (amask[b * NAa + t] == 0) ? -1e8f : q;   // FP32
    }
}

// ---------------------------------------------------------------------------
extern "C" void kernel_launch(void* const* d_in, const int* in_sizes, int n_in,
                              void* d_out, int out_size, void* d_ws, size_t ws_size,
                              hipStream_t stream) {
    (void)in_sizes; (void)n_in; (void)out_size;
    const float* x     = (const float*)d_in[0];
    const int* ei      = (const int*)d_in[1];
    const int* cnid    = (const int*)d_in[4];
    const int* amask   = (const int*)d_in[5];
    const float* panw  = (const float*)d_in[6];
    const float* l1w   = (const float*)d_in[7];
    const float* l1b   = (const float*)d_in[8];
    const float* n1w   = (const float*)d_in[9];
    const float* n1b   = (const float*)d_in[10];
    const float* n1ms  = (const float*)d_in[11];
    const float* poolp = (const float*)d_in[12];
    const float* poolb = (const float*)d_in[13];
    const float* gwl   = (const float*)d_in[14];
    const float* gbl   = (const float*)d_in[15];
    const float* gwr   = (const float*)d_in[16];
    const float* gbr   = (const float*)d_in[17];
    const float* gatt  = (const float*)d_in[18];
    const float* gbias = (const float*)d_in[19];
    const float* n2w   = (const float*)d_in[20];
    const float* n2b   = (const float*)d_in[21];
    const float* n2ms  = (const float*)d_in[22];
    const float* v1w   = (const float*)d_in[23];
    const float* v1b   = (const float*)d_in[24];
    const float* v2w   = (const float*)d_in[25];
    const float* v2b   = (const float*)d_in[26];
    const float* v3w   = (const float*)d_in[27];
    const float* v3b   = (const float*)d_in[28];
    const float* a1w   = (const float*)d_in[29];
    const float* a1b   = (const float*)d_in[30];
    const float* a2w   = (const float*)d_in[31];
    const float* a2b   = (const float*)d_in[32];
    const float* a3w   = (const float*)d_in[33];
    const float* a3b   = (const float*)d_in[34];
    float* out         = (float*)d_out;

    // ws layout (bytes): Rb 512K | csrF | csrT | floats
    uint8_t* wsb = (uint8_t*)d_ws;
    uint32_t* Rb   = (uint32_t*)wsb;
    unsigned short* csrF = (unsigned short*)(wsb + 524288);
    unsigned short* csrT = csrF + (size_t)MAXD * 8192;
    float* h_raw  = (float*)(csrT + (size_t)MAXD * 8192);
    float* x1     = h_raw + (size_t)NNt * 3;
    float* colsum = x1 + (size_t)NNt * 3;
    float* g_raw  = colsum + NNt;
    const size_t needed = 524288 + 2 * (size_t)MAXD * 8192 * 2 +
                          ((size_t)(2 * NNt * 3 + NNt + BB * KPAD * 3)) * 4;
    if (ws_size < needed) return;

    r16_build<<<dim3(16), dim3(512), 0, stream>>>(ei, csrF, csrT);
    r16_mid<<<dim3(16, 20), dim3(512), 0, stream>>>(x, csrF, csrT, panw, l1w, l1b,
                                                    h_raw, colsum, Rb);
    r16_poolgat<<<dim3(16, 8), dim3(512), 0, stream>>>(h_raw, colsum, Rb,
                                                       n1w, n1b, n1ms, poolp, poolb,
                                                       gwl, gbl, gwr, gbr, gatt, gbias,
                                                       x1, g_raw);
    r16_head<<<dim3(16), dim3(512), 0, stream>>>(g_raw, x1, x, cnid, amask,
                                                 n2w, n2b, n2ms, v1w, v1b, v2w, v2b, v3w, v3b,
                                                 a1w, a1b, a2w, a2b, a3w, a3b, out);
}

// Round 17
// 208.657 us; speedup vs baseline: 1.1867x; 1.1867x over previous
//
#include <hip/hip_runtime.h>
#include <hip/hip_bf16.h>
#include <stdint.h>
#include <math.h>

// PANConcDQL round 17 -- math identical to r15/r16 (passed, absmax 0.0).
// Recombination: r15's parallel build path (memset+scatter+extract: 192/64
// blocks, no serial edge scans) + r16's shfl-stat poolgat & head + r15 mid.
// r16 lesson: 16-block fused build = 60us latency chain; parallel trio ~30us.
#define BB   16
#define NPn  512
#define LLp  20
#define NAa  50
#define KKk  410
#define NNt  (BB * NPn)   // 8192
#define EEe  (6 * NNt)    // 49152
#define NFf  13
#define KPAD 416
#define KP2  448          // padded GAT staging width (7*64)
#define EPSf 1e-5f
#define QCLMP 1e6f
#define MAXD 28
#define PADR 512

__device__ __forceinline__ float r17_sane(float v) {
    if (!(v == v)) return 0.0f;
    return fminf(fmaxf(v, -1e15f), 1e15f);
}

// ---------------------------------------------------------------------------
// K1: edge scatter -> global bitsets (one edge per thread, 192 blocks).
__global__ __launch_bounds__(256) void r17_scatter(
    const int* __restrict__ ei,
    uint32_t* __restrict__ fwdb, uint32_t* __restrict__ trsb)
{
    const int e = blockIdx.x * 256 + threadIdx.x;
    if (e < EEe) {
        const int src = ei[e], dst = ei[EEe + e];
        atomicOr(&fwdb[(size_t)dst * 16 + ((src & 511) >> 5)], 1u << (src & 31));
        atomicOr(&trsb[(size_t)src * 16 + ((dst & 511) >> 5)], 1u << (dst & 31));
    }
}

// ---------------------------------------------------------------------------
// K2: bitset -> CSR planes (u16, csr[j*8192+node], coalesced stores).
__global__ __launch_bounds__(256) void r17_extract(
    const uint32_t* __restrict__ fwdb, const uint32_t* __restrict__ trsb,
    unsigned short* __restrict__ csrF, unsigned short* __restrict__ csrT)
{
    const int t = blockIdx.x * 256 + threadIdx.x;      // 0..16383
    const int node = t & 8191;
    const uint32_t* bs = (t < 8192) ? (fwdb + (size_t)node * 16)
                                    : (trsb + (size_t)node * 16);
    unsigned short* cs = (t < 8192) ? csrF : csrT;
    int cnt = 0;
    for (int w = 0; w < 16; ++w) {
        uint32_t bits = bs[w];
        while (bits) {
            const int u = (w << 5) + __ffs(bits) - 1;
            bits &= bits - 1;
            if (cnt < MAXD) cs[(size_t)cnt * 8192 + node] = (unsigned short)u;
            ++cnt;
        }
    }
    for (int j = cnt; j < MAXD; ++j) cs[(size_t)j * 8192 + node] = PADR;
}

// ---------------------------------------------------------------------------
// K3: mid, grid (16,20) x 512 (r15_mid verbatim).
__global__ __launch_bounds__(512) void r17_mid(
    const float* __restrict__ x,
    const unsigned short* __restrict__ csrF,
    const unsigned short* __restrict__ csrT,
    const float* __restrict__ panw,
    const float* __restrict__ l1w, const float* __restrict__ l1b,
    float* __restrict__ h_raw, float* __restrict__ colsum,
    uint32_t* __restrict__ Rb)
{
    __shared__ __align__(16) uint32_t sbuf[1047];
    float* pa  = (float*)sbuf;             // 513
    float* pb  = (float*)(sbuf + 513);     // 513
    float* wsh = (float*)(sbuf + 1026);    // 21
    const int b = blockIdx.x, y = blockIdx.y, t = threadIdx.x;
    const int node = b * 512 + t;

    if (y < 4) {
        const int c = y;
        int iF[MAXD];
#pragma unroll
        for (int j = 0; j < MAXD; ++j) iF[j] = (int)csrF[(size_t)j * 8192 + node];
        if (t < 21) wsh[t] = panw[t];

        pa[t] = 1.0f;
        if (t == 0) { pa[512] = 0.0f; pb[512] = 0.0f; }
        __syncthreads();
        float dacc = wsh[0];
        {
            float* rp = pa; float* rn = pb;
            for (int i = 1; i <= LLp; ++i) {
                float tv[MAXD];
#pragma unroll
                for (int j = 0; j < MAXD; ++j) tv[j] = rp[iF[j]];
                float s = 0.0f;
#pragma unroll
                for (int j = 0; j < MAXD; ++j) s += tv[j];
                rn[t] = s;
                dacc += wsh[i] * s;
                __syncthreads();
                float* tp = rp; rp = rn; rn = tp;
            }
        }
        const float d0 = (dacc > 0.0f) ? 1.0f / sqrtf(dacc) : 0.0f;

        int idx[MAXD];
        if (c == 3) {
#pragma unroll
            for (int j = 0; j < MAXD; ++j) idx[j] = (int)csrT[(size_t)j * 8192 + node];
        } else {
#pragma unroll
            for (int j = 0; j < MAXD; ++j) idx[j] = iF[j];
        }
        float seed;
        if (c < 3) {
            float xw = 0.0f;
            const float* xr = x + (size_t)node * NFf;
            for (int f = 0; f < NFf; ++f) xw += xr[f] * l1w[f * 3 + c];
            seed = d0 * xw;
        } else {
            seed = d0;
        }
        pa[t] = seed;
        if (t == 0) { pa[512] = 0.0f; pb[512] = 0.0f; }
        __syncthreads();
        float acc = wsh[0] * seed;
        {
            float* rp = pa; float* rn = pb;
            for (int i = 1; i <= LLp; ++i) {
                float tv[MAXD];
#pragma unroll
                for (int j = 0; j < MAXD; ++j) tv[j] = rp[idx[j]];
                float s = 0.0f;
#pragma unroll
                for (int j = 0; j < MAXD; ++j) s += tv[j];
                rn[t] = s;
                acc += wsh[i] * s;
                __syncthreads();
                float* tp = rp; rp = rn; rn = tp;
            }
        }
        if (c < 3) h_raw[(size_t)node * 3 + c] = r17_sane(d0 * acc + l1b[c]);
        else       colsum[node] = r17_sane(d0 * acc);
    } else {
        const int q = y - 4;
        int iF[MAXD];
#pragma unroll
        for (int j = 0; j < MAXD; ++j) iF[j] = (int)csrF[(size_t)j * 8192 + node];
        uint32_t* R1 = sbuf;
        uint32_t* R2 = sbuf + 513;
        R1[t] = ((t >> 5) == q) ? (1u << (t & 31)) : 0u;
        if (t == 0) { R1[512] = 0u; R2[512] = 0u; }
        __syncthreads();
        uint32_t* Rp = R1; uint32_t* Rn = R2;
        for (int i = 0; i < LLp; ++i) {
            uint32_t tv[MAXD];
#pragma unroll
            for (int j = 0; j < MAXD; ++j) tv[j] = Rp[iF[j]];
            uint32_t r = Rp[t];
#pragma unroll
            for (int j = 0; j < MAXD; ++j) r |= tv[j];
            Rn[t] = r;
            __syncthreads();
            uint32_t* tp = Rp; Rp = Rn; Rn = tp;
        }
        Rb[(size_t)node * 16 + q] = Rp[t];
    }
}

// ---------------------------------------------------------------------------
// K4: poolgat, grid (16,8) x 512 (r16 version: shfl stats, padded staging).
__global__ __launch_bounds__(512) void r17_poolgat(
    const float* __restrict__ h_raw,
    const float* __restrict__ colsum,
    const uint32_t* __restrict__ Rb,
    const float* n1w, const float* n1b, const float* n1ms,
    const float* poolp, const float* poolb,
    const float* gwl, const float* gbl,
    const float* gwr, const float* gbr,
    const float* gatt, const float* gbias,
    float* __restrict__ x1,
    float* __restrict__ g_raw)
{
    __shared__ __align__(16) uint32_t pg[10744];
    float* sc   = (float*)pg;                  // 512
    float* mv   = (float*)(pg + 512);          // 8
    float* wred = (float*)(pg + 520);          // 48
    float* xpS  = (float*)(pg + 568);          // 1248 (416*3)
    int*   kidx = (int*)(pg + 1816);           // 416
    float* xlS  = (float*)(pg + 2232);         // 1344 (448*3)
    uint32_t* RT = pg + 3576;                  // 16*448 = 7168
    const int b = blockIdx.x, y = blockIdx.y, t = threadIdx.x;
    const int lane = t & 63, wv = t >> 6;
    const float inv_n = 1.0f / (float)NNt;

    float hv0[16], hv1[16], hv2[16];
    float p0 = 0.0f, p1 = 0.0f, p2 = 0.0f;
#pragma unroll
    for (int k = 0; k < 16; ++k) {
        const float* hr = h_raw + (size_t)(k * 512 + t) * 3;
        hv0[k] = hr[0]; hv1[k] = hr[1]; hv2[k] = hr[2];
        p0 += hv0[k]; p1 += hv1[k]; p2 += hv2[k];
    }
#pragma unroll
    for (int off = 32; off; off >>= 1) {
        p0 += __shfl_xor(p0, off); p1 += __shfl_xor(p1, off); p2 += __shfl_xor(p2, off);
    }
    if (lane == 0) { wred[wv * 3 + 0] = p0; wred[wv * 3 + 1] = p1; wred[wv * 3 + 2] = p2; }
    __syncthreads();
    if (t < 3) {
        float s = 0.0f;
        for (int w = 0; w < 8; ++w) s += wred[w * 3 + t];
        mv[t] = s * inv_n;
    }
    __syncthreads();
    const float mm0 = n1ms[0] * mv[0], mm1 = n1ms[1] * mv[1], mm2 = n1ms[2] * mv[2];
    float q0 = 0.0f, q1 = 0.0f, q2 = 0.0f;
#pragma unroll
    for (int k = 0; k < 16; ++k) {
        const float d0 = hv0[k] - mm0, d1 = hv1[k] - mm1, d2 = hv2[k] - mm2;
        q0 += d0 * d0; q1 += d1 * d1; q2 += d2 * d2;
    }
#pragma unroll
    for (int off = 32; off; off >>= 1) {
        q0 += __shfl_xor(q0, off); q1 += __shfl_xor(q1, off); q2 += __shfl_xor(q2, off);
    }
    if (lane == 0) { wred[wv * 3 + 0] = q0; wred[wv * 3 + 1] = q1; wred[wv * 3 + 2] = q2; }
    __syncthreads();
    if (t < 3) {
        float s = 0.0f;
        for (int w = 0; w < 8; ++w) s += wred[w * 3 + t];
        mv[3 + t] = s * inv_n;
    }
    __syncthreads();

    const float mmv[3] = { mm0, mm1, mm2 };
    float xv[3];
#pragma unroll
    for (int c = 0; c < 3; ++c) {
        const float iv = 1.0f / sqrtf(fmaxf(mv[3 + c], 0.0f) + EPSf);
        const float o  = h_raw[(size_t)(b * NPn + t) * 3 + c] - mmv[c];
        const float tt = n1w[c] * o * iv + n1b[c];
        xv[c] = fmaxf(tt, 0.0f);
        if (y == 0) x1[(size_t)(b * NPn + t) * 3 + c] = xv[c];
    }
    float s = poolb[0] * (xv[0] * poolp[0] + xv[1] * poolp[1] + xv[2] * poolp[2])
            + poolb[1] * colsum[b * NPn + t];
    s = tanhf(s);
    if (!(s == s)) s = 0.0f;
    sc[t] = s;
    __syncthreads();
    int cnt = 0;
    for (int u = 0; u < NPn; ++u) {
        const float su = sc[u];
        cnt += ((su > s) || (su == s && u < t)) ? 1 : 0;   // lax.top_k tie-break
    }
    if (cnt < KKk) {                       // rank-count bijection
        kidx[cnt] = t;
        xpS[cnt * 3 + 0] = xv[0] * s;
        xpS[cnt * 3 + 1] = xv[1] * s;
        xpS[cnt * 3 + 2] = xv[2] * s;
    }
    __syncthreads();

    float Wl[9], Wr[9];
#pragma unroll
    for (int i2 = 0; i2 < 9; ++i2) { Wl[i2] = gwl[i2]; Wr[i2] = gwr[i2]; }
    const float Bl0 = gbl[0], Bl1 = gbl[1], Bl2 = gbl[2];
    const float Br0 = gbr[0], Br1 = gbr[1], Br2 = gbr[2];
    const float At0 = gatt[0], At1 = gatt[1], At2 = gatt[2];
    const float Gb0 = gbias[0], Gb1 = gbias[1], Gb2 = gbias[2];
    if (t < KP2) {
        const int j = t;
        if (j < KKk) {
            const float c0 = xpS[j * 3 + 0];
            const float c1 = xpS[j * 3 + 1];
            const float c2 = xpS[j * 3 + 2];
            xlS[j * 3 + 0] = c0 * Wl[0] + c1 * Wl[3] + c2 * Wl[6] + Bl0;
            xlS[j * 3 + 1] = c0 * Wl[1] + c1 * Wl[4] + c2 * Wl[7] + Bl1;
            xlS[j * 3 + 2] = c0 * Wl[2] + c1 * Wl[5] + c2 * Wl[8] + Bl2;
            const uint32_t* rr = Rb + (size_t)(b * NPn + kidx[j]) * 16;
#pragma unroll
            for (int w = 0; w < 16; ++w) RT[w * KP2 + j] = rr[w];
        } else {
            xlS[j * 3 + 0] = 0.0f; xlS[j * 3 + 1] = 0.0f; xlS[j * 3 + 2] = 0.0f;
#pragma unroll
            for (int w = 0; w < 16; ++w) RT[w * KP2 + j] = 0u;
        }
    }
    __syncthreads();

    const int wid = y * 8 + wv;                    // 0..63
    for (int i = wid; i < KKk; i += 64) {
        const float c0 = xpS[i * 3 + 0];
        const float c1 = xpS[i * 3 + 1];
        const float c2 = xpS[i * 3 + 2];
        const float xr0 = c0 * Wr[0] + c1 * Wr[3] + c2 * Wr[6] + Br0;
        const float xr1 = c0 * Wr[1] + c1 * Wr[4] + c2 * Wr[7] + Br1;
        const float xr2 = c0 * Wr[2] + c1 * Wr[5] + c2 * Wr[8] + Br2;
        const int bi = kidx[i];
        const uint32_t mbit = 1u << (bi & 31);
        const uint32_t* Rw = &RT[(bi >> 5) * KP2];
        float mx = -3e38f, lsum = 0.0f, b0 = 0.0f, b1 = 0.0f, b2 = 0.0f;
#pragma unroll
        for (int it = 0; it < 7; ++it) {
            const int j = lane + it * 64;          // < 448
            const uint32_t rw = Rw[j];             // unconditional batched loads
            const float xl0 = xlS[j * 3 + 0];
            const float xl1 = xlS[j * 3 + 1];
            const float xl2 = xlS[j * 3 + 2];
            const bool valid = (rw & mbit) || (j == i);   // pads auto-invalid
            float e0 = xr0 + xl0; e0 = e0 > 0.0f ? e0 : 0.2f * e0;
            float e1 = xr1 + xl1; e1 = e1 > 0.0f ? e1 : 0.2f * e1;
            float e2 = xr2 + xl2; e2 = e2 > 0.0f ? e2 : 0.2f * e2;
            const float sv = At0 * e0 + At1 * e1 + At2 * e2;
            if (valid) {
                if (sv > mx) {
                    const float r = __expf(mx - sv);
                    lsum *= r; b0 *= r; b1 *= r; b2 *= r;
                    mx = sv;
                }
                const float pj = __expf(sv - mx);
                lsum += pj;
                b0 += pj * xl0; b1 += pj * xl1; b2 += pj * xl2;
            }
        }
#pragma unroll
        for (int off = 32; off; off >>= 1) {       // butterfly LSE merge
            const float mo = __shfl_xor(mx, off);
            const float lo = __shfl_xor(lsum, off);
            const float d0 = __shfl_xor(b0, off);
            const float d1 = __shfl_xor(b1, off);
            const float d2 = __shfl_xor(b2, off);
            const float M  = fmaxf(mx, mo);
            const float ea = __expf(mx - M), eb = __expf(mo - M);
            lsum = lsum * ea + lo * eb;
            b0 = b0 * ea + d0 * eb;
            b1 = b1 * ea + d1 * eb;
            b2 = b2 * ea + d2 * eb;
            mx = M;
        }
        if (lane == 0) {
            const float rl = 1.0f / fmaxf(lsum, 1e-30f);
            g_raw[(size_t)(b * KPAD + i) * 3 + 0] = r17_sane(b0 * rl + Gb0);
            g_raw[(size_t)(b * KPAD + i) * 3 + 1] = r17_sane(b1 * rl + Gb1);
            g_raw[(size_t)(b * KPAD + i) * 3 + 2] = r17_sane(b2 * rl + Gb2);
        }
    }
}

// ---------------------------------------------------------------------------
// K5: head (r16 version: shfl stats).
__global__ __launch_bounds__(512) void r17_head(
    const float* __restrict__ g_raw,
    const float* __restrict__ x1,
    const float* __restrict__ x,
    const int* __restrict__ cnid,
    const int* __restrict__ amask,
    const float* n2w, const float* n2b, const float* n2ms,
    const float* v1w, const float* v1b,
    const float* v2w, const float* v2b,
    const float* v3w, const float* v3b,
    const float* a1w, const float* a1b,
    const float* a2w, const float* a2b,
    const float* a3w, const float* a3b,
    float* __restrict__ out)
{
    __shared__ float wred[24];
    __shared__ float mv[6];
    __shared__ float gp[3];
    __shared__ float feat[19];
    __shared__ float h1a[10], h1v[10], h2a[5], h2v[5];
    __shared__ float a3[50];
    __shared__ float vout_s, amean_s;
    const int b = blockIdx.x, t = threadIdx.x;
    const int lane = t & 63, wv = t >> 6;
    const float denom = 1.0f / (float)(BB * KKk);

    float gv0[13], gv1[13], gv2[13];
    float p0 = 0.0f, p1 = 0.0f, p2 = 0.0f;
#pragma unroll
    for (int k = 0; k < 13; ++k) {
        const int r = k * 512 + t;
        float q0 = 0.0f, q1 = 0.0f, q2 = 0.0f;
        if (r < BB * KKk) {
            const int bq = r / KKk, iq = r - bq * KKk;
            const float* gr = g_raw + (size_t)(bq * KPAD + iq) * 3;
            q0 = gr[0]; q1 = gr[1]; q2 = gr[2];
        }
        gv0[k] = q0; gv1[k] = q1; gv2[k] = q2;
        p0 += q0; p1 += q1; p2 += q2;
    }
#pragma unroll
    for (int off = 32; off; off >>= 1) {
        p0 += __shfl_xor(p0, off); p1 += __shfl_xor(p1, off); p2 += __shfl_xor(p2, off);
    }
    if (lane == 0) { wred[wv * 3 + 0] = p0; wred[wv * 3 + 1] = p1; wred[wv * 3 + 2] = p2; }
    __syncthreads();
    if (t < 3) {
        float s = 0.0f;
        for (int w = 0; w < 8; ++w) s += wred[w * 3 + t];
        mv[t] = s * denom;
    }
    __syncthreads();
    const float mm0 = n2ms[0] * mv[0], mm1 = n2ms[1] * mv[1], mm2 = n2ms[2] * mv[2];
    float q0a = 0.0f, q1a = 0.0f, q2a = 0.0f;
#pragma unroll
    for (int k = 0; k < 13; ++k) {
        const int r = k * 512 + t;
        if (r < BB * KKk) {
            const float d0 = gv0[k] - mm0, d1 = gv1[k] - mm1, d2 = gv2[k] - mm2;
            q0a += d0 * d0; q1a += d1 * d1; q2a += d2 * d2;
        }
    }
#pragma unroll
    for (int off = 32; off; off >>= 1) {
        q0a += __shfl_xor(q0a, off); q1a += __shfl_xor(q1a, off); q2a += __shfl_xor(q2a, off);
    }
    if (lane == 0) { wred[wv * 3 + 0] = q0a; wred[wv * 3 + 1] = q1a; wred[wv * 3 + 2] = q2a; }
    __syncthreads();
    if (t < 3) {
        float s = 0.0f;
        for (int w = 0; w < 8; ++w) s += wred[w * 3 + t];
        mv[3 + t] = s * denom;
    }
    __syncthreads();

    const float mmv[3] = { mm0, mm1, mm2 };
    float s3[3] = { 0.0f, 0.0f, 0.0f };
    if (t < KKk) {
        const size_t r = (size_t)(b * KPAD + t) * 3;
#pragma unroll
        for (int c = 0; c < 3; ++c) {
            const float iv = 1.0f / sqrtf(fmaxf(mv[3 + c], 0.0f) + EPSf);
            s3[c] = fmaxf((g_raw[r + c] - mmv[c]) * iv * n2w[c] + n2b[c], 0.0f);
        }
    }
    float g0 = s3[0], g1 = s3[1], g2 = s3[2];
#pragma unroll
    for (int off = 32; off; off >>= 1) {
        g0 += __shfl_xor(g0, off); g1 += __shfl_xor(g1, off); g2 += __shfl_xor(g2, off);
    }
    if (lane == 0) { wred[wv * 3 + 0] = g0; wred[wv * 3 + 1] = g1; wred[wv * 3 + 2] = g2; }
    __syncthreads();
    if (t < 3) {
        float s = 0.0f;
        for (int w = 0; w < 8; ++w) s += wred[w * 3 + t];
        gp[t] = s;
    }
    __syncthreads();

    if (t < 19) {
        const int gidx = cnid[b] + b * KKk;        // faithful: pooled-K offsets
        float fv;
        if (t < 13)      fv = x[(size_t)gidx * NFf + t];
        else if (t < 16) fv = x1[(size_t)gidx * 3 + (t - 13)];
        else             fv = gp[t - 16];
        feat[t] = fv;
    }
    __syncthreads();

    if (t < 10) {
        float s = a1b[t];
        for (int f = 0; f < 19; ++f) s += feat[f] * a1w[f * 10 + t];
        h1a[t] = fmaxf(s, 0.0f);
    } else if (t >= 64 && t < 74) {
        const int j = t - 64;
        float s = v1b[j];
        for (int f = 0; f < 19; ++f) s += feat[f] * v1w[f * 10 + j];
        h1v[j] = fmaxf(s, 0.0f);
    }
    __syncthreads();
    if (t < 5) {
        float s = a2b[t];
        for (int k = 0; k < 10; ++k) s += h1a[k] * a2w[k * 5 + t];
        h2a[t] = fmaxf(s, 0.0f);
    } else if (t >= 64 && t < 69) {
        const int j = t - 64;
        float s = v2b[j];
        for (int k = 0; k < 10; ++k) s += h1v[k] * v2w[k * 5 + j];
        h2v[j] = fmaxf(s, 0.0f);
    }
    __syncthreads();
    if (t < 50) {
        float s = a3b[t];
        for (int k = 0; k < 5; ++k) s += h2a[k] * a3w[k * 50 + t];
        a3[t] = s;
    } else if (t == 64) {
        float s = v3b[0];
        for (int k = 0; k < 5; ++k) s += h2v[k] * v3w[k];
        vout_s = s;
    }
    __syncthreads();
    if (t == 0) {
        float s = 0.0f;
        for (int k = 0; k < 50; ++k) s += a3[k];
        amean_s = s * (1.0f / 50.0f);
    }
    __syncthreads();
    if (t < 50) {
        float q = vout_s + a3[t] - amean_s;
        if (!(q == q)) q = 0.0f;
        q = fminf(fmaxf(q, -QCLMP), QCLMP);
        out[b * NAa + t] = (amask[b * NAa + t] == 0) ? -1e8f : q;   // FP32
    }
}

// ---------------------------------------------------------------------------
extern "C" void kernel_launch(void* const* d_in, const int* in_sizes, int n_in,
                              void* d_out, int out_size, void* d_ws, size_t ws_size,
                              hipStream_t stream) {
    (void)in_sizes; (void)n_in; (void)out_size;
    const float* x     = (const float*)d_in[0];
    const int* ei      = (const int*)d_in[1];
    const int* cnid    = (const int*)d_in[4];
    const int* amask   = (const int*)d_in[5];
    const float* panw  = (const float*)d_in[6];
    const float* l1w   = (const float*)d_in[7];
    const float* l1b   = (const float*)d_in[8];
    const float* n1w   = (const float*)d_in[9];
    const float* n1b   = (const float*)d_in[10];
    const float* n1ms  = (const float*)d_in[11];
    const float* poolp = (const float*)d_in[12];
    const float* poolb = (const float*)d_in[13];
    const float* gwl   = (const float*)d_in[14];
    const float* gbl   = (const float*)d_in[15];
    const float* gwr   = (const float*)d_in[16];
    const float* gbr   = (const float*)d_in[17];
    const float* gatt  = (const float*)d_in[18];
    const float* gbias = (const float*)d_in[19];
    const float* n2w   = (const float*)d_in[20];
    const float* n2b   = (const float*)d_in[21];
    const float* n2ms  = (const float*)d_in[22];
    const float* v1w   = (const float*)d_in[23];
    const float* v1b   = (const float*)d_in[24];
    const float* v2w   = (const float*)d_in[25];
    const float* v2b   = (const float*)d_in[26];
    const float* v3w   = (const float*)d_in[27];
    const float* v3b   = (const float*)d_in[28];
    const float* a1w   = (const float*)d_in[29];
    const float* a1b   = (const float*)d_in[30];
    const float* a2w   = (const float*)d_in[31];
    const float* a2b   = (const float*)d_in[32];
    const float* a3w   = (const float*)d_in[33];
    const float* a3b   = (const float*)d_in[34];
    float* out         = (float*)d_out;

    // ws layout (bytes): fwdb 512K | trsb 512K | Rb 512K | csrF | csrT | floats
    uint8_t* wsb = (uint8_t*)d_ws;
    uint32_t* fwdb = (uint32_t*)wsb;
    uint32_t* trsb = (uint32_t*)(wsb + 524288);
    uint32_t* Rb   = (uint32_t*)(wsb + 1048576);
    unsigned short* csrF = (unsigned short*)(wsb + 1572864);
    unsigned short* csrT = csrF + (size_t)MAXD * 8192;
    float* h_raw  = (float*)(csrT + (size_t)MAXD * 8192);
    float* x1     = h_raw + (size_t)NNt * 3;
    float* colsum = x1 + (size_t)NNt * 3;
    float* g_raw  = colsum + NNt;
    const size_t needed = 1572864 + 2 * (size_t)MAXD * 8192 * 2 +
                          ((size_t)(2 * NNt * 3 + NNt + BB * KPAD * 3)) * 4;
    if (ws_size < needed) return;

    hipMemsetAsync(fwdb, 0, 1048576, stream);            // both bitsets
    r17_scatter<<<dim3((EEe + 255) / 256), dim3(256), 0, stream>>>(ei, fwdb, trsb);
    r17_extract<<<dim3(64), dim3(256), 0, stream>>>(fwdb, trsb, csrF, csrT);
    r17_mid<<<dim3(16, 20), dim3(512), 0, stream>>>(x, csrF, csrT, panw, l1w, l1b,
                                                    h_raw, colsum, Rb);
    r17_poolgat<<<dim3(16, 8), dim3(512), 0, stream>>>(h_raw, colsum, Rb,
                                                       n1w, n1b, n1ms, poolp, poolb,
                                                       gwl, gbl, gwr, gbr, gatt, gbias,
                                                       x1, g_raw);
    r17_head<<<dim3(16), dim3(512), 0, stream>>>(g_raw, x1, x, cnid, amask,
                                                 n2w, n2b, n2ms, v1w, v1b, v2w, v2b, v3w, v3b,
                                                 a1w, a1b, a2w, a2b, a3w, a3b, out);
}